// Round 1
// baseline (2373.323 us; speedup 1.0000x reference)
//
#include <hip/hip_runtime.h>

#define B_ 2048
#define T_ 128
#define S_ 256
#define V_ 29
#define E_ 32
#define H_ 64

// ---------------------------------------------------------------------------
// Precompute (runs once per launch, 1 block):
//   gate_emb[v][g] = b_ih[g] + b_hh[g] + sum_e emb_table[v,e] * W_ih[g,e]
//   Wcat[g][0:64]  = W_ih[g][32:96]   (context part)
//   Wcat[g][64:128]= W_hh[g][0:64]
// ---------------------------------------------------------------------------
__global__ __launch_bounds__(256) void precompute_kernel(
    const float* __restrict__ emb_table, const float* __restrict__ W_ih,
    const float* __restrict__ W_hh, const float* __restrict__ b_ih,
    const float* __restrict__ b_hh, float* __restrict__ ws)
{
    const int g = threadIdx.x;
    float wemb[32];
#pragma unroll
    for (int e = 0; e < 32; ++e) wemb[e] = W_ih[g * 96 + e];
    const float bb = b_ih[g] + b_hh[g];
    for (int v = 0; v < V_; ++v) {
        float acc = bb;
#pragma unroll
        for (int e = 0; e < 32; ++e) acc = fmaf(emb_table[v * 32 + e], wemb[e], acc);
        ws[v * 256 + g] = acc;   // coalesced
    }
    float* wcat = ws + V_ * 256;
#pragma unroll
    for (int k = 0; k < 64; ++k) wcat[g * 128 + k] = W_ih[g * 96 + 32 + k];
#pragma unroll
    for (int k = 0; k < 64; ++k) wcat[g * 128 + 64 + k] = W_hh[g * 64 + k];
}

// ---------------------------------------------------------------------------
// Main decoder: 1 block = 1 batch row, 256 threads, T=128 sequential steps.
// enc row (64 KB) swizzled in LDS; gate weights in registers (thread g owns
// gate g's 128-wide row); fc_W distributed 16 floats/thread.
// ---------------------------------------------------------------------------
__global__ __launch_bounds__(256, 2) void decoder_kernel(
    const int* __restrict__ y, const float* __restrict__ h0,
    const float* __restrict__ c0, const float* __restrict__ enc,
    const float* __restrict__ fc_W, const float* __restrict__ fc_b,
    const float* __restrict__ ws, float* __restrict__ out)
{
    // element (s, h) lives at float4 index s*16 + ((h/4 + s) & 15), comp h&3
    __shared__ float4 encS[S_ * 16];                  // 64 KB
    __shared__ float attn[256];                       // also reused as gates buf
    __shared__ float ctxpart[256];                    // [wave][h]
    __shared__ __align__(16) float vec128[128];       // [context(64) | h(64)]
    __shared__ float cvec[64];
    __shared__ int yrow[T_];
    __shared__ float red[128];                        // logits reduction
    __shared__ float redmax[4];
    __shared__ float redsum[4];

    const int tid = threadIdx.x;
    const int b = blockIdx.x;
    const int wid = tid >> 6;
    const int lane = tid & 63;

    // --- per-thread weight registers ---
    const float* wcat = ws + V_ * 256;
    float4 w4[32];
#pragma unroll
    for (int q = 0; q < 32; ++q) w4[q] = ((const float4*)(wcat + tid * 128))[q];

    const int v = tid & 31;
    const int jj = tid >> 5;  // 0..7, k-range 16*jj of combined[128]
    float4 fcw4[4];
    float fcb = 0.f;
    if (v < V_) {
#pragma unroll
        for (int q = 0; q < 4; ++q)
            fcw4[q] = ((const float4*)(fc_W + v * 128 + jj * 16))[q];
        fcb = fc_b[v];
    } else {
#pragma unroll
        for (int q = 0; q < 4; ++q) fcw4[q] = make_float4(0.f, 0.f, 0.f, 0.f);
    }

    // --- stage enc row into LDS (swizzled), init h/c/y ---
    {
        const float4* encg = (const float4*)(enc + (size_t)b * S_ * H_);
#pragma unroll
        for (int i = 0; i < 16; ++i) {
            int f4 = i * 256 + tid;
            int s = f4 >> 4, h4 = f4 & 15;
            encS[s * 16 + ((h4 + s) & 15)] = encg[f4];
        }
    }
    if (tid < 64) {
        vec128[64 + tid] = h0[b * 64 + tid];
        cvec[tid] = c0[b * 64 + tid];
    }
    if (tid < T_) yrow[tid] = y[b * T_ + tid];
    __syncthreads();

    for (int t = 0; t < T_; ++t) {
        const int yt = yrow[t];
        const float ge = ws[yt * 256 + tid];  // gate_emb, L2-hot, used late

        // ---- scores: thread computes score[s=tid] = enc[s,:] . h_prev
        float sc = 0.f;
#pragma unroll
        for (int i = 0; i < 16; ++i) {
            float4 e4 = encS[tid * 16 + ((i + tid) & 15)];
            float4 h4 = *(const float4*)&vec128[64 + 4 * i];
            sc += e4.x * h4.x + e4.y * h4.y + e4.z * h4.z + e4.w * h4.w;
        }

        // ---- softmax over 256 scores
        float m = sc;
#pragma unroll
        for (int off = 32; off >= 1; off >>= 1) m = fmaxf(m, __shfl_xor(m, off));
        if (lane == 0) redmax[wid] = m;
        __syncthreads();  // B1
        m = fmaxf(fmaxf(redmax[0], redmax[1]), fmaxf(redmax[2], redmax[3]));
        float e = __expf(sc - m);
        float ssum = e;
#pragma unroll
        for (int off = 32; off >= 1; off >>= 1) ssum += __shfl_xor(ssum, off);
        if (lane == 0) redsum[wid] = ssum;
        __syncthreads();  // B2
        const float tot = redsum[0] + redsum[1] + redsum[2] + redsum[3];
        attn[tid] = e / tot;
        __syncthreads();  // B3

        // ---- context: wave wid reduces its 64-s chunk for all 64 h
        {
            float acc = 0.f;
            const int h = lane;
#pragma unroll
            for (int i4 = 0; i4 < 16; ++i4) {
                float4 a4 = *(const float4*)&attn[64 * wid + 4 * i4];
#pragma unroll
                for (int q = 0; q < 4; ++q) {
                    int s = 64 * wid + 4 * i4 + q;
                    float ev = ((const float*)&encS[s * 16 + (((h >> 2) + s) & 15)])[h & 3];
                    acc = fmaf((&a4.x)[q], ev, acc);
                }
            }
            ctxpart[wid * 64 + h] = acc;
        }
        __syncthreads();  // B4
        if (tid < 64)
            vec128[tid] = ctxpart[tid] + ctxpart[64 + tid] + ctxpart[128 + tid] + ctxpart[192 + tid];
        __syncthreads();  // B5

        // ---- gates: thread g = tid, weights in registers
        float gacc = ge;
#pragma unroll
        for (int q = 0; q < 32; ++q) {
            float4 x4 = *(const float4*)&vec128[4 * q];
            gacc += w4[q].x * x4.x + w4[q].y * x4.y + w4[q].z * x4.z + w4[q].w * x4.w;
        }
        attn[tid] = gacc;  // reuse attn[] as gates buffer
        __syncthreads();  // B6

        // ---- LSTM pointwise (wave 0 only)
        if (tid < 64) {
            float gi = attn[tid], gf = attn[64 + tid], gg = attn[128 + tid], go = attn[192 + tid];
            float si = 1.f / (1.f + __expf(-gi));
            float sf = 1.f / (1.f + __expf(-gf));
            float so = 1.f / (1.f + __expf(-go));
            float tg = 1.f - 2.f / (__expf(2.f * gg) + 1.f);
            float cn = sf * cvec[tid] + si * tg;
            cvec[tid] = cn;
            float hn = so * (1.f - 2.f / (__expf(2.f * cn) + 1.f));
            vec128[64 + tid] = hn;
        }
        __syncthreads();  // B7

        // ---- logits: combined[k] = vec128[k ^ 64]; thread (v, jj) does 16 k's
        {
            const int base = (jj < 4) ? (64 + 16 * jj) : (16 * jj - 64);
            float acc = 0.f;
#pragma unroll
            for (int q = 0; q < 4; ++q) {
                float4 c4 = *(const float4*)&vec128[base + 4 * q];
                acc += fcw4[q].x * c4.x + fcw4[q].y * c4.y + fcw4[q].z * c4.z + fcw4[q].w * c4.w;
            }
            acc += __shfl_xor(acc, 32);               // fold jj pairs
            if ((tid & 32) == 0) red[wid * 32 + v] = acc;
        }
        __syncthreads();  // B8
        if (tid < V_) {
            float r = red[tid] + red[32 + tid] + red[64 + tid] + red[96 + tid] + fcb;
            out[((size_t)b * T_ + t) * V_ + tid] = r;
        }
        // red[] is only rewritten at next iteration's B8 zone — no extra barrier
    }
}

extern "C" void kernel_launch(void* const* d_in, const int* in_sizes, int n_in,
                              void* d_out, int out_size, void* d_ws, size_t ws_size,
                              hipStream_t stream)
{
    const int*   y    = (const int*)  d_in[0];
    const float* h0   = (const float*)d_in[1];
    const float* c0   = (const float*)d_in[2];
    const float* enc  = (const float*)d_in[3];
    const float* emb  = (const float*)d_in[4];
    const float* W_ih = (const float*)d_in[5];
    const float* W_hh = (const float*)d_in[6];
    const float* b_ih = (const float*)d_in[7];
    const float* b_hh = (const float*)d_in[8];
    const float* fc_W = (const float*)d_in[9];
    const float* fc_b = (const float*)d_in[10];
    float* ws  = (float*)d_ws;   // needs (29*256 + 256*128)*4 = 157 KB
    float* out = (float*)d_out;

    precompute_kernel<<<1, 256, 0, stream>>>(emb, W_ih, W_hh, b_ih, b_hh, ws);
    decoder_kernel<<<B_, 256, 0, stream>>>(y, h0, c0, enc, fc_W, fc_b, ws, out);
}